// Round 10
// baseline (79.864 us; speedup 1.0000x reference)
//
#include <hip/hip_runtime.h>
#include <hip/hip_bf16.h>
#include <math.h>

typedef __attribute__((ext_vector_type(8))) _Float16 half8;
typedef __attribute__((ext_vector_type(4))) float f32x4;

#define EMBD 128
#define H1 256
#define H2 128
#define SLEN 50

// Branch-free GELU, exact-erf form via Abramowitz-Stegun 7.1.26 (|err|<=1.5e-7).
__device__ __forceinline__ float gelu_exact(float h) {
    float ah = fabsf(h);
    float d  = fmaf(0.23163845f, ah, 1.0f);
    float t;
    asm("v_rcp_f32 %0, %1" : "=v"(t) : "v"(d));
    float p = fmaf(1.061405429f, t, -1.453152027f);
    p = fmaf(p, t, 1.421413741f);
    p = fmaf(p, t, -0.284496736f);
    p = fmaf(p, t, 0.254829592f);
    p = p * t;
    float e;                                   // v_exp_f32 computes 2^x
    float x2 = h * h * -0.72134752f;           // -h^2/2 * log2(e)
    asm("v_exp_f32 %0, %1" : "=v"(e) : "v"(x2));
    float er = fmaf(-p, e, 1.0f);
    return fmaf(0.5f * ah, er, 0.5f * h);
}

// Raw barrier WITHOUT vmcnt drain: LDS ordering only (lgkmcnt), so in-flight
// global prefetches survive the barrier.
#define BARRIER_LDS() asm volatile("s_waitcnt lgkmcnt(0)\n\ts_barrier" ::: "memory")

// ---------------------------------------------------------------------------
// Prep: w1/w2 fp32 row-major -> fp16 MFMA B-fragments. BYTE-IDENTICAL to the
// passing R9 prep (fragment layout unchanged).
// ---------------------------------------------------------------------------
__global__ __launch_bounds__(256) void prep_weights(
    const float* __restrict__ w1, const float* __restrict__ w2,
    half8* __restrict__ ws)
{
    int f = blockIdx.x * 256 + threadIdx.x;   // 0..8191
    half8 v;
    if (f < 4096) {
        int lane = f & 63;
        int nt = (f >> 6) & 3, kt = (f >> 8) & 3, w = (f >> 10) & 3;
        int col = w * 64 + nt * 16 + (lane & 15);
        int kb  = kt * 32 + (lane >> 4) * 8;
        #pragma unroll
        for (int i = 0; i < 8; ++i) v[i] = (_Float16)w1[(size_t)(kb + i) * H1 + col];
        ws[f] = v;
    } else {
        int f2 = f - 4096;
        int lane = f2 & 63;
        int nt = (f2 >> 6) & 1, kt = (f2 >> 7) & 7, w = (f2 >> 10) & 3;
        int col = w * 32 + nt * 16 + (lane & 15);
        int kb  = kt * 32 + (lane >> 4) * 8;
        #pragma unroll
        for (int i = 0; i < 8; ++i) v[i] = (_Float16)w2[(size_t)(kb + i) * H2 + col];
        ws[4096 + f2] = v;
    }
}

// ---------------------------------------------------------------------------
// Main: 1024 blocks x 256 threads. Each block owns 4 rows (bid + i*grid),
// processed as 2 PAIRS; each pair's two rows share one 32-token M-tile
// (row A = M-subtile 0, row B = M-subtile 1), halving serial tile count.
// Per-row numeric order identical to the passing R6/R9 kernels.
// ---------------------------------------------------------------------------
__global__ __launch_bounds__(256, 2) void entity_encoder_kernel(
    const int* __restrict__ ids, const int* __restrict__ lens,
    const float* __restrict__ emb, const float* __restrict__ ln1g,
    const float* __restrict__ ln1b, const float* __restrict__ b1,
    const float* __restrict__ b2, const float* __restrict__ ln2g,
    const float* __restrict__ ln2b, const float* __restrict__ fcw,
    const float* __restrict__ fcb, const half8* __restrict__ wfrag,
    float* __restrict__ out)
{
    const int tid = threadIdx.x;
    const int w  = tid >> 6;   // wave 0..3
    const int l  = tid & 63;   // lane
    const int ln = l & 15;
    const int lg = l >> 4;
    const int g16 = w * 4 + lg;   // 16-lane group id 0..15 = token-in-half-tile

    __shared__ __align__(16) _Float16 x_lds[32][EMBD + 8];
    __shared__ __align__(16) _Float16 h1_lds[32][H1 + 8];
    __shared__ float pool_lds[2][H2];

    // ---- weight fragments (layout identical to R6/R9) ----
    half8 w1f[4][4];
    #pragma unroll
    for (int kt = 0; kt < 4; ++kt)
      #pragma unroll
      for (int nt = 0; nt < 4; ++nt)
        w1f[kt][nt] = wfrag[((w * 4 + kt) * 4 + nt) * 64 + l];
    half8 w2f[8][2];
    #pragma unroll
    for (int kt = 0; kt < 8; ++kt)
      #pragma unroll
      for (int nt = 0; nt < 2; ++nt)
        w2f[kt][nt] = wfrag[4096 + ((w * 8 + kt) * 2 + nt) * 64 + l];

    float g1r[8], b1r[8];
    #pragma unroll
    for (int i = 0; i < 8; ++i) { g1r[i] = ln1g[ln * 8 + i]; b1r[i] = ln1b[ln * 8 + i]; }
    float b1v[4];
    #pragma unroll
    for (int nt = 0; nt < 4; ++nt) b1v[nt] = b1[w * 64 + nt * 16 + ln];
    float b2v[2];
    #pragma unroll
    for (int nt = 0; nt < 2; ++nt) b2v[nt] = b2[w * 32 + nt * 16 + ln];
    float g2a = ln2g[l], g2c = ln2g[l + 64];
    float b2a = ln2b[l], b2c = ln2b[l + 64];
    float fwa = fcw[l],  fwc = fcw[l + 64];
    float fcb0 = fcb[0];

    // ---- 4 rows, strided; pairs (0,1) and (2,3) ----
    int rows[4], Ts[4];
    #pragma unroll
    for (int i = 0; i < 4; ++i) {
        rows[i] = blockIdx.x + i * (int)gridDim.x;
        int T = lens[rows[i]];
        Ts[i] = T < 1 ? 1 : (T > SLEN ? SLEN : T);
    }

    // ---- prefetch pair 0, tile 0, both slots ----
    float4 pa0[2], pa1[2]; bool va[2];
    #pragma unroll
    for (int s = 0; s < 2; ++s) {
        va[s] = (g16 < Ts[s]);
        if (va[s]) {
            int id = ids[rows[s] * SLEN + g16];
            const float4* src = (const float4*)(emb + (size_t)id * EMBD + ln * 8);
            pa0[s] = src[0]; pa1[s] = src[1];
        }
    }

    for (int j = 0; j < 2; ++j) {
        const int TA = Ts[2 * j], TB = Ts[2 * j + 1];
        const int ntA = (TA + 15) >> 4, ntB = (TB + 15) >> 4;
        const int ntiles = ntA > ntB ? ntA : ntB;
        float poolr[2][2];
        #pragma unroll
        for (int m = 0; m < 2; ++m) { poolr[m][0] = -INFINITY; poolr[m][1] = -INFINITY; }

        for (int mt = 0; mt < ntiles; ++mt) {
            // ---- LN1 for both slots (independent trees -> ILP) ----
            #pragma unroll
            for (int s = 0; s < 2; ++s) {
                half8 xo;
                if (va[s]) {
                    float v[8] = {pa0[s].x, pa0[s].y, pa0[s].z, pa0[s].w,
                                  pa1[s].x, pa1[s].y, pa1[s].z, pa1[s].w};
                    float sm = 0.f, ss = 0.f;
                    #pragma unroll
                    for (int k = 0; k < 8; ++k) { sm += v[k]; ss += v[k] * v[k]; }
                    #pragma unroll
                    for (int m = 1; m < 16; m <<= 1) {
                        sm += __shfl_xor(sm, m, 64);
                        ss += __shfl_xor(ss, m, 64);
                    }
                    float mu  = sm * (1.f / 128.f);
                    float var = ss * (1.f / 128.f) - mu * mu;
                    float rs  = rsqrtf(var + 1e-12f);
                    #pragma unroll
                    for (int k = 0; k < 8; ++k)
                        xo[k] = (_Float16)((v[k] - mu) * rs * g1r[k] + b1r[k]);
                } else {
                    #pragma unroll
                    for (int k = 0; k < 8; ++k) xo[k] = (_Float16)0.f;
                }
                *(half8*)&x_lds[s * 16 + g16][ln * 8] = xo;
            }

            // ---- issue next prefetch: (j, mt+1) else (j+1, 0); survives barriers ----
            float4 pb0[2], pb1[2]; bool vb[2] = {false, false};
            {
                int nj = j, nmt = mt + 1;
                if (nmt >= ntiles) { nj = j + 1; nmt = 0; }
                if (nj < 2) {
                    #pragma unroll
                    for (int s = 0; s < 2; ++s) {
                        int tn = nmt * 16 + g16;
                        if (tn < Ts[2 * nj + s]) {
                            vb[s] = true;
                            int id = ids[rows[2 * nj + s] * SLEN + tn];
                            const float4* src = (const float4*)(emb + (size_t)id * EMBD + ln * 8);
                            pb0[s] = src[0]; pb1[s] = src[1];
                        }
                    }
                }
            }

            BARRIER_LDS();   // x_lds ready (no vmcnt drain)

            // ---- GEMM1: 32 tokens x 256 cols; wave w -> cols w*64..+63 ----
            f32x4 acc[2][4];
            #pragma unroll
            for (int m = 0; m < 2; ++m)
              #pragma unroll
              for (int nt = 0; nt < 4; ++nt) acc[m][nt] = (f32x4){0,0,0,0};
            #pragma unroll
            for (int kt = 0; kt < 4; ++kt) {
                half8 a0 = *(const half8*)&x_lds[ln][kt * 32 + lg * 8];
                half8 a1 = *(const half8*)&x_lds[16 + ln][kt * 32 + lg * 8];
                #pragma unroll
                for (int nt = 0; nt < 4; ++nt) {
                    acc[0][nt] = __builtin_amdgcn_mfma_f32_16x16x32_f16(a0, w1f[kt][nt], acc[0][nt], 0, 0, 0);
                    acc[1][nt] = __builtin_amdgcn_mfma_f32_16x16x32_f16(a1, w1f[kt][nt], acc[1][nt], 0, 0, 0);
                }
            }
            // bias + GELU -> h1_lds (fp16)
            #pragma unroll
            for (int m = 0; m < 2; ++m)
              #pragma unroll
              for (int nt = 0; nt < 4; ++nt) {
                int col = w * 64 + nt * 16 + ln;
                #pragma unroll
                for (int g2 = 0; g2 < 4; ++g2) {
                    int row = m * 16 + lg * 4 + g2;
                    float h = acc[m][nt][g2] + b1v[nt];
                    h1_lds[row][col] = (_Float16)gelu_exact(h);
                }
              }

            BARRIER_LDS();   // h1_lds ready (no vmcnt drain)

            // ---- GEMM2: wave w -> cols w*32..+31 ----
            f32x4 acc2[2][2];
            #pragma unroll
            for (int m = 0; m < 2; ++m) { acc2[m][0] = (f32x4){0,0,0,0}; acc2[m][1] = (f32x4){0,0,0,0}; }
            #pragma unroll
            for (int kt = 0; kt < 8; ++kt) {
                half8 a0 = *(const half8*)&h1_lds[ln][kt * 32 + lg * 8];
                half8 a1 = *(const half8*)&h1_lds[16 + ln][kt * 32 + lg * 8];
                #pragma unroll
                for (int nt = 0; nt < 2; ++nt) {
                    acc2[0][nt] = __builtin_amdgcn_mfma_f32_16x16x32_f16(a0, w2f[kt][nt], acc2[0][nt], 0, 0, 0);
                    acc2[1][nt] = __builtin_amdgcn_mfma_f32_16x16x32_f16(a1, w2f[kt][nt], acc2[1][nt], 0, 0, 0);
                }
            }
            // ---- masked max-pool per row-slot (same reduce order as R6/R9) ----
            #pragma unroll
            for (int m = 0; m < 2; ++m) {
                const int Tm = m ? TB : TA;
                #pragma unroll
                for (int nt = 0; nt < 2; ++nt) {
                    float tm = -INFINITY;
                    #pragma unroll
                    for (int g2 = 0; g2 < 4; ++g2) {
                        int trow = lg * 4 + g2;
                        bool valid = (mt * 16 + trow) < Tm;
                        float h = acc2[m][nt][g2] + b2v[nt];
                        if (valid) tm = fmaxf(tm, h);
                    }
                    tm = fmaxf(tm, __shfl_xor(tm, 16, 64));
                    tm = fmaxf(tm, __shfl_xor(tm, 32, 64));
                    poolr[m][nt] = fmaxf(poolr[m][nt], tm);
                }
            }

            #pragma unroll
            for (int s = 0; s < 2; ++s) {
                if (vb[s]) { pa0[s] = pb0[s]; pa1[s] = pb1[s]; }
                va[s] = vb[s];
            }
        }

        // ---- pair epilogue: pools -> LDS -> LN2 -> fc for both rows ----
        if (lg == 0) {
            #pragma unroll
            for (int m = 0; m < 2; ++m)
              #pragma unroll
              for (int nt = 0; nt < 2; ++nt)
                pool_lds[m][w * 32 + nt * 16 + ln] = poolr[m][nt];
        }
        BARRIER_LDS();

        if (w < 2) {   // wave 0 -> row A, wave 1 -> row B
            float v0 = pool_lds[w][l], v1 = pool_lds[w][l + 64];
            float s = v0 + v1, ss = v0 * v0 + v1 * v1;
            #pragma unroll
            for (int m = 1; m < 64; m <<= 1) {
                s  += __shfl_xor(s,  m, 64);
                ss += __shfl_xor(ss, m, 64);
            }
            float mu  = s * (1.f / 128.f);
            float var = ss * (1.f / 128.f) - mu * mu;
            float rs  = rsqrtf(var + 1e-12f);
            float n0 = (v0 - mu) * rs * g2a + b2a;
            float n1 = (v1 - mu) * rs * g2c + b2c;
            float dot = n0 * fwa + n1 * fwc;
            #pragma unroll
            for (int m = 1; m < 64; m <<= 1) dot += __shfl_xor(dot, m, 64);
            if (l == 0) out[rows[2 * j + w]] = dot + fcb0;
        }
        BARRIER_LDS();   // pool_lds safe before next pair's writes
    }
}

extern "C" void kernel_launch(void* const* d_in, const int* in_sizes, int n_in,
                              void* d_out, int out_size, void* d_ws, size_t ws_size,
                              hipStream_t stream) {
    const int*   ids  = (const int*)d_in[0];
    const int*   lens = (const int*)d_in[1];
    const float* emb  = (const float*)d_in[2];
    const float* ln1g = (const float*)d_in[3];
    const float* ln1b = (const float*)d_in[4];
    const float* w1   = (const float*)d_in[5];
    const float* b1   = (const float*)d_in[6];
    const float* w2   = (const float*)d_in[7];
    const float* b2   = (const float*)d_in[8];
    const float* ln2g = (const float*)d_in[9];
    const float* ln2b = (const float*)d_in[10];
    const float* fcw  = (const float*)d_in[11];
    const float* fcb  = (const float*)d_in[12];
    float* out = (float*)d_out;
    half8* ws = (half8*)d_ws;   // needs 128 KiB

    hipLaunchKernelGGL(prep_weights, dim3(32), dim3(256), 0, stream, w1, w2, ws);

    int nblocks = out_size / 4;   // 1024 blocks; block b owns rows b + i*1024
    hipLaunchKernelGGL(entity_encoder_kernel, dim3(nblocks), dim3(256), 0, stream,
                       ids, lens, emb, ln1g, ln1b, b1, b2, ln2g, ln2b, fcw, fcb,
                       ws, out);
}

// Round 11
// 68.052 us; speedup vs baseline: 1.1736x; 1.1736x over previous
//
#include <hip/hip_runtime.h>
#include <hip/hip_bf16.h>
#include <math.h>

typedef __attribute__((ext_vector_type(8))) _Float16 half8;
typedef __attribute__((ext_vector_type(4))) _Float16 half4;
typedef __attribute__((ext_vector_type(4))) float f32x4;

#define EMBD 128
#define H1 256
#define H2 128
#define SLEN 50
#define NR 4            // rows per block (grid = 4096/NR = 1024)

// Branch-free GELU, exact-erf form via Abramowitz-Stegun 7.1.26 (|err|<=1.5e-7).
__device__ __forceinline__ float gelu_exact(float h) {
    float ah = fabsf(h);
    float d  = fmaf(0.23163845f, ah, 1.0f);
    float t;
    asm("v_rcp_f32 %0, %1" : "=v"(t) : "v"(d));
    float p = fmaf(1.061405429f, t, -1.453152027f);
    p = fmaf(p, t, 1.421413741f);
    p = fmaf(p, t, -0.284496736f);
    p = fmaf(p, t, 0.254829592f);
    p = p * t;
    float e;                                   // v_exp_f32 computes 2^x
    float x2 = h * h * -0.72134752f;           // -h^2/2 * log2(e)
    asm("v_exp_f32 %0, %1" : "=v"(e) : "v"(x2));
    float er = fmaf(-p, e, 1.0f);
    return fmaf(0.5f * ah, er, 0.5f * h);
}

// Raw barrier WITHOUT vmcnt drain: LDS ordering only (lgkmcnt), so in-flight
// global prefetches survive the barrier.
#define BARRIER_LDS() asm volatile("s_waitcnt lgkmcnt(0)\n\ts_barrier" ::: "memory")

// ---------------------------------------------------------------------------
// Prep: w1/w2 fp32 row-major -> fp16 MFMA fragments. BYTE-IDENTICAL to R9.
// (w1 fragments double as A-operands of the transposed GEMM1: A-frag
//  row=lane&15 and B-frag col=lane&15 have the same lane mapping.)
// ---------------------------------------------------------------------------
__global__ __launch_bounds__(256) void prep_weights(
    const float* __restrict__ w1, const float* __restrict__ w2,
    half8* __restrict__ ws)
{
    int f = blockIdx.x * 256 + threadIdx.x;   // 0..8191
    half8 v;
    if (f < 4096) {
        int lane = f & 63;
        int nt = (f >> 6) & 3, kt = (f >> 8) & 3, w = (f >> 10) & 3;
        int col = w * 64 + nt * 16 + (lane & 15);
        int kb  = kt * 32 + (lane >> 4) * 8;
        #pragma unroll
        for (int i = 0; i < 8; ++i) v[i] = (_Float16)w1[(size_t)(kb + i) * H1 + col];
        ws[f] = v;
    } else {
        int f2 = f - 4096;
        int lane = f2 & 63;
        int nt = (f2 >> 6) & 1, kt = (f2 >> 7) & 7, w = (f2 >> 10) & 3;
        int col = w * 32 + nt * 16 + (lane & 15);
        int kb  = kt * 32 + (lane >> 4) * 8;
        #pragma unroll
        for (int i = 0; i < 8; ++i) v[i] = (_Float16)w2[(size_t)(kb + i) * H2 + col];
        ws[4096 + f2] = v;
    }
}

// ---------------------------------------------------------------------------
// Main: 1024 blocks x 256 threads, NR=4 strided rows. Software-pipelined:
// per tile ONE barrier: [gather(t+2) | GEMM1T+GELU(t) | LN1(t+1)] bar [GEMM2+pool(t)]
// x_lds / h1_lds double-buffered. Per-row arithmetic identical to R9.
// ---------------------------------------------------------------------------
__global__ __launch_bounds__(256) void entity_encoder_kernel(
    const int* __restrict__ ids, const int* __restrict__ lens,
    const float* __restrict__ emb, const float* __restrict__ ln1g,
    const float* __restrict__ ln1b, const float* __restrict__ b1,
    const float* __restrict__ b2, const float* __restrict__ ln2g,
    const float* __restrict__ ln2b, const float* __restrict__ fcw,
    const float* __restrict__ fcb, const half8* __restrict__ wfrag,
    float* __restrict__ out)
{
    const int tid = threadIdx.x;
    const int w  = tid >> 6;   // wave 0..3
    const int l  = tid & 63;   // lane
    const int ln = l & 15;
    const int lg = l >> 4;
    const int g16 = w * 4 + lg;   // token-in-tile owned by this 16-lane group

    __shared__ __align__(16) _Float16 x_lds[2][16][EMBD + 8];
    __shared__ __align__(16) _Float16 h1_lds[2][16][H1 + 8];
    __shared__ float pool_lds[H2];

    // ---- weight fragments (identical to R9; 128 regs, unified-file resident)
    half8 w1f[4][4];
    #pragma unroll
    for (int kt = 0; kt < 4; ++kt)
      #pragma unroll
      for (int mt = 0; mt < 4; ++mt)
        w1f[kt][mt] = wfrag[((w * 4 + kt) * 4 + mt) * 64 + l];
    half8 w2f[8][2];
    #pragma unroll
    for (int kt = 0; kt < 8; ++kt)
      #pragma unroll
      for (int nt = 0; nt < 2; ++nt)
        w2f[kt][nt] = wfrag[4096 + ((w * 8 + kt) * 2 + nt) * 64 + l];

    float g1r[8], b1r[8];
    #pragma unroll
    for (int i = 0; i < 8; ++i) { g1r[i] = ln1g[ln * 8 + i]; b1r[i] = ln1b[ln * 8 + i]; }
    // bias for transposed-GEMM1 output: thread owns H1 cols w*64+mt*16+lg*4 .. +3
    f32x4 b1tv[4];
    #pragma unroll
    for (int mt = 0; mt < 4; ++mt)
        b1tv[mt] = *(const f32x4*)&b1[w * 64 + mt * 16 + lg * 4];
    float b2v[2];
    #pragma unroll
    for (int nt = 0; nt < 2; ++nt) b2v[nt] = b2[w * 32 + nt * 16 + ln];
    float g2a = ln2g[l], g2c = ln2g[l + 64];
    float b2a = ln2b[l], b2c = ln2b[l + 64];
    float fwa = fcw[l],  fwc = fcw[l + 64];
    float fcb0 = fcb[0];

    int rows[NR], Ts[NR];
    #pragma unroll
    for (int i = 0; i < NR; ++i) {
        rows[i] = blockIdx.x + i * (int)gridDim.x;
        int T = lens[rows[i]];
        Ts[i] = T < 1 ? 1 : (T > SLEN ? SLEN : T);
    }

    // ---- prologue: gather+LN1 tile (0,0) -> x[0]; issue gather of next tile ----
    float4 pa0, pa1; bool va;
    va = (g16 < Ts[0]);
    if (va) {
        int id = ids[rows[0] * SLEN + g16];
        const float4* src = (const float4*)(emb + (size_t)id * EMBD + ln * 8);
        pa0 = src[0]; pa1 = src[1];
    }
    {
        half8 xo;
        if (va) {
            float v[8] = {pa0.x, pa0.y, pa0.z, pa0.w, pa1.x, pa1.y, pa1.z, pa1.w};
            float s = 0.f, ss = 0.f;
            #pragma unroll
            for (int k = 0; k < 8; ++k) { s += v[k]; ss += v[k] * v[k]; }
            #pragma unroll
            for (int m = 1; m < 16; m <<= 1) {
                s  += __shfl_xor(s,  m, 64);
                ss += __shfl_xor(ss, m, 64);
            }
            float mu  = s * (1.f / 128.f);
            float var = ss * (1.f / 128.f) - mu * mu;
            float rs  = rsqrtf(var + 1e-12f);
            #pragma unroll
            for (int k = 0; k < 8; ++k)
                xo[k] = (_Float16)((v[k] - mu) * rs * g1r[k] + b1r[k]);
        } else {
            #pragma unroll
            for (int k = 0; k < 8; ++k) xo[k] = (_Float16)0.f;
        }
        *(half8*)&x_lds[0][g16][ln * 8] = xo;
    }
    // (i1,t1) = tile after (0,0); gather it into pa
    int i1 = 0, t1 = 1;
    if (t1 >= ((Ts[0] + 15) >> 4)) { i1 = 1; t1 = 0; }
    va = false;
    if (i1 < NR) {
        int tn = t1 * 16 + g16;
        if (tn < Ts[i1]) {
            va = true;
            int id = ids[rows[i1] * SLEN + tn];
            const float4* src = (const float4*)(emb + (size_t)id * EMBD + ln * 8);
            pa0 = src[0]; pa1 = src[1];
        }
    }
    BARRIER_LDS();   // x[0] visible
    int cur = 0;

    for (int i = 0; i < NR; ++i) {
        const int T = Ts[i];
        const int ntiles = (T + 15) >> 4;
        float pool0 = -INFINITY, pool1 = -INFINITY;

        for (int t = 0; t < ntiles; ++t) {
            // ---- issue gather for tile (i2,t2) = advance(i1,t1) -> pb ----
            int i2 = i1, t2 = t1;
            float4 pb0, pb1; bool vb = false;
            if (i1 < NR) {
                t2 = t1 + 1;
                if (t2 >= ((Ts[i1] + 15) >> 4)) { i2 = i1 + 1; t2 = 0; }
                if (i2 < NR) {
                    int tn = t2 * 16 + g16;
                    if (tn < Ts[i2]) {
                        vb = true;
                        int id = ids[rows[i2] * SLEN + tn];
                        const float4* src = (const float4*)(emb + (size_t)id * EMBD + ln * 8);
                        pb0 = src[0]; pb1 = src[1];
                    }
                }
            }

            // ---- B(t): transposed GEMM1 + GELU -> h1[cur] ----
            const _Float16* xb = &x_lds[cur][0][0];
            _Float16*       hb = &h1_lds[cur][0][0];
            f32x4 acc[4] = {{0,0,0,0},{0,0,0,0},{0,0,0,0},{0,0,0,0}};
            #pragma unroll
            for (int kt = 0; kt < 4; ++kt) {
                half8 bfrag = *(const half8*)(xb + ln * (EMBD + 8) + kt * 32 + lg * 8);
                #pragma unroll
                for (int mt = 0; mt < 4; ++mt)
                    acc[mt] = __builtin_amdgcn_mfma_f32_16x16x32_f16(w1f[kt][mt], bfrag, acc[mt], 0, 0, 0);
            }
            // thread owns token ln, H1 cols w*64+mt*16+lg*4..+3 -> packed b64 writes
            #pragma unroll
            for (int mt = 0; mt < 4; ++mt) {
                half4 hv;
                #pragma unroll
                for (int g2 = 0; g2 < 4; ++g2) {
                    float h = acc[mt][g2] + b1tv[mt][g2];
                    hv[g2] = (_Float16)gelu_exact(h);
                }
                *(half4*)(hb + ln * (H1 + 8) + w * 64 + mt * 16 + lg * 4) = hv;
            }

            // ---- A(t+1): LN1 of tile (i1,t1) -> x[cur^1] ----
            if (i1 < NR) {
                half8 xo;
                if (va) {
                    float v[8] = {pa0.x, pa0.y, pa0.z, pa0.w, pa1.x, pa1.y, pa1.z, pa1.w};
                    float s = 0.f, ss = 0.f;
                    #pragma unroll
                    for (int k = 0; k < 8; ++k) { s += v[k]; ss += v[k] * v[k]; }
                    #pragma unroll
                    for (int m = 1; m < 16; m <<= 1) {
                        s  += __shfl_xor(s,  m, 64);
                        ss += __shfl_xor(ss, m, 64);
                    }
                    float mu  = s * (1.f / 128.f);
                    float var = ss * (1.f / 128.f) - mu * mu;
                    float rs  = rsqrtf(var + 1e-12f);
                    #pragma unroll
                    for (int k = 0; k < 8; ++k)
                        xo[k] = (_Float16)((v[k] - mu) * rs * g1r[k] + b1r[k]);
                } else {
                    #pragma unroll
                    for (int k = 0; k < 8; ++k) xo[k] = (_Float16)0.f;
                }
                *(half8*)&x_lds[cur ^ 1][g16][ln * 8] = xo;
            }

            BARRIER_LDS();   // publishes h1[cur] and x[cur^1]; gathers stay in flight

            // ---- C(t): GEMM2 + masked pool (reads h1[cur]) ----
            f32x4 acc2[2] = {{0,0,0,0},{0,0,0,0}};
            #pragma unroll
            for (int kt = 0; kt < 8; ++kt) {
                half8 a = *(const half8*)(hb + ln * (H1 + 8) + kt * 32 + lg * 8);
                #pragma unroll
                for (int nt = 0; nt < 2; ++nt)
                    acc2[nt] = __builtin_amdgcn_mfma_f32_16x16x32_f16(a, w2f[kt][nt], acc2[nt], 0, 0, 0);
            }
            {
                float tm0 = -INFINITY, tm1 = -INFINITY;
                #pragma unroll
                for (int g2 = 0; g2 < 4; ++g2) {
                    int trow = lg * 4 + g2;
                    bool valid = (t * 16 + trow) < T;
                    float h0  = acc2[0][g2] + b2v[0];
                    float h1v = acc2[1][g2] + b2v[1];
                    if (valid) { tm0 = fmaxf(tm0, h0); tm1 = fmaxf(tm1, h1v); }
                }
                tm0 = fmaxf(tm0, __shfl_xor(tm0, 16, 64));
                tm0 = fmaxf(tm0, __shfl_xor(tm0, 32, 64));
                tm1 = fmaxf(tm1, __shfl_xor(tm1, 16, 64));
                tm1 = fmaxf(tm1, __shfl_xor(tm1, 32, 64));
                pool0 = fmaxf(pool0, tm0);
                pool1 = fmaxf(pool1, tm1);
            }

            // ---- rotate pipeline state ----
            if (vb) { pa0 = pb0; pa1 = pb1; }
            va = vb; i1 = i2; t1 = t2;
            cur ^= 1;
        }

        // ---- row epilogue: pool -> LN2 -> fc (lgkm-only barriers) ----
        if (l < 16) {
            pool_lds[w * 32 + ln]      = pool0;
            pool_lds[w * 32 + 16 + ln] = pool1;
        }
        BARRIER_LDS();

        float v0 = pool_lds[l], v1 = pool_lds[l + 64];
        float s = v0 + v1, ss = v0 * v0 + v1 * v1;
        #pragma unroll
        for (int m = 1; m < 64; m <<= 1) {
            s  += __shfl_xor(s,  m, 64);
            ss += __shfl_xor(ss, m, 64);
        }
        float mu  = s * (1.f / 128.f);
        float var = ss * (1.f / 128.f) - mu * mu;
        float rs  = rsqrtf(var + 1e-12f);
        float n0 = (v0 - mu) * rs * g2a + b2a;
        float n1 = (v1 - mu) * rs * g2c + b2c;
        float dot = n0 * fwa + n1 * fwc;
        #pragma unroll
        for (int m = 1; m < 64; m <<= 1) dot += __shfl_xor(dot, m, 64);
        if (tid == 0) out[rows[i]] = dot + fcb0;

        BARRIER_LDS();   // protect pool_lds before next row's writes
    }
}

extern "C" void kernel_launch(void* const* d_in, const int* in_sizes, int n_in,
                              void* d_out, int out_size, void* d_ws, size_t ws_size,
                              hipStream_t stream) {
    const int*   ids  = (const int*)d_in[0];
    const int*   lens = (const int*)d_in[1];
    const float* emb  = (const float*)d_in[2];
    const float* ln1g = (const float*)d_in[3];
    const float* ln1b = (const float*)d_in[4];
    const float* w1   = (const float*)d_in[5];
    const float* b1   = (const float*)d_in[6];
    const float* w2   = (const float*)d_in[7];
    const float* b2   = (const float*)d_in[8];
    const float* ln2g = (const float*)d_in[9];
    const float* ln2b = (const float*)d_in[10];
    const float* fcw  = (const float*)d_in[11];
    const float* fcb  = (const float*)d_in[12];
    float* out = (float*)d_out;
    half8* ws = (half8*)d_ws;   // needs 128 KiB

    hipLaunchKernelGGL(prep_weights, dim3(32), dim3(256), 0, stream, w1, w2, ws);

    int nblocks = out_size / NR;   // 1024 blocks, 4 strided rows each
    hipLaunchKernelGGL(entity_encoder_kernel, dim3(nblocks), dim3(256), 0, stream,
                       ids, lens, emb, ln1g, ln1b, b1, b2, ln2g, ln2b, fcw, fcb,
                       ws, out);
}